// Round 4
// baseline (9452.350 us; speedup 1.0000x reference)
//
#include <hip/hip_runtime.h>

// LSTM B=64, S=512, D=H=1024 on MI355X (gfx950).
// R7: self-signaling tagged h-ring -- hop-collapsed cross-block chain.
// 2 recurrence groups (32 batches) x 64 j-slices = 128 blocks x 1024 thr.
// Full K=2048 weights in VGPRs (16 waves = 4 K-quarters x 4 row-groups).
//
// Cross-block protocol (NO slot array, NO arrive counter, NO vmcnt on chain):
//   ring unit = 16B = 12B payload (6 bf16 h) + 4B epoch tag, written by ONE
//   global_store_dwordx4 sc0 sc1 (single 16B transaction => tag+payload
//   visible atomically). Producer: gates -> 6 shfl gather -> store, fire
//   and forget. Consumer thread owns 12 units: pipelined tag polls (all 12
//   in flight), backoff s_sleep on miss, then payload loads + swizzled LDS
//   writes. Chain = store-commit -> poll-hit -> payload RTT. 2 barriers/step.
// Ring layout per (group, parity): [64 js][32 eb][3 units x 16B] = 96 KB.
// Unit i3 covers block-local j = i3*6 .. i3*6+5 (i3=2: 4 j + pad).

typedef short short8 __attribute__((ext_vector_type(8)));
typedef float float4v __attribute__((ext_vector_type(4)));
typedef int int4v __attribute__((ext_vector_type(4)));
typedef unsigned long long u64;

__device__ __forceinline__ short f2bf(float f) {
  union { float f; unsigned u; } v; v.f = f;
  unsigned r = (v.u + 0x7fffu + ((v.u >> 16) & 1u)) >> 16;  // RNE
  return (short)r;
}

__device__ __forceinline__ float sigm(float z) {
  float e = __expf(-fabsf(z));
  float p = 1.0f / (1.0f + e);
  return z >= 0.0f ? p : 1.0f - p;
}

__device__ __forceinline__ float tanh_s(float z) {
  float e = __expf(-2.0f * fabsf(z));
  float r = (1.0f - e) / (1.0f + e);
  return z >= 0.0f ? r : -r;
}

// one-time x fp32 [b][s][d] -> bf16 [s][b][d]
__global__ __launch_bounds__(256) void xconv(const float* __restrict__ x,
                                             short* __restrict__ xbf) {
  const int gid = blockIdx.x * 256 + threadIdx.x;
  const long i8 = (long)gid * 8;
  const int d  = (int)(i8 & 1023);
  const int bs = (int)(i8 >> 10);
  const int s  = bs & 511;
  const int b  = bs >> 9;
  const float4v* src = (const float4v*)(x + i8);
  float4v v0 = src[0], v1 = src[1];
  short8 o;
  o[0]=f2bf(v0[0]); o[1]=f2bf(v0[1]); o[2]=f2bf(v0[2]); o[3]=f2bf(v0[3]);
  o[4]=f2bf(v1[0]); o[5]=f2bf(v1[1]); o[6]=f2bf(v1[2]); o[7]=f2bf(v1[3]);
  *(short8*)(xbf + (((size_t)(s * 64 + b)) << 10) + d) = o;
}

template <bool XBF>
__global__ __launch_bounds__(1024, 4) void lstm_persist(
    const float* __restrict__ x, const short* __restrict__ xbf,
    const float* __restrict__ Wx, const float* __restrict__ bx,
    const float* __restrict__ Wh, const float* __restrict__ bh,
    float* __restrict__ out, char* ring)
{
  __shared__ short hS[32 * 1024];      // 64 KB staged h, XOR-swizzled rows of 2 KB
  __shared__ float red[4][32][68];     // 34.8 KB [kq][batch][n], +4 pad

  const int tid  = threadIdx.x;
  const int bid  = blockIdx.x;
  const int g    = bid & 1;        // batch group
  const int js   = bid >> 1;       // j-slice 0..63
  const int lane = tid & 63;
  const int w    = tid >> 6;       // wave 0..15
  const int kq   = w >> 2;         // K-quarter: 0,1 -> x, 2,3 -> h
  const int rg   = w & 3;          // row-group (16 rows each)
  const int l15  = lane & 15;
  const int lh   = lane >> 4;

  // ---- static weights: 16 rows per wave, n = l15 = jj*4+gi ----
  short8 bw[16];
  {
    const int gi  = l15 & 3;
    const int jj  = l15 >> 2;
    const int row = gi * 1024 + js * 16 + rg * 4 + jj;
    const float* Wsrc = (kq < 2) ? (Wx + (size_t)row * 1024 + kq * 512)
                                 : (Wh + (size_t)row * 1024 + (kq - 2) * 512);
    #pragma unroll
    for (int ks = 0; ks < 16; ++ks) {
      const float* p = Wsrc + ks * 32 + lh * 8;
      float4v v0 = *(const float4v*)p;
      float4v v1 = *(const float4v*)(p + 4);
      short8 o;
      o[0]=f2bf(v0[0]); o[1]=f2bf(v0[1]); o[2]=f2bf(v0[2]); o[3]=f2bf(v0[3]);
      o[4]=f2bf(v1[0]); o[5]=f2bf(v1[1]); o[6]=f2bf(v1[2]); o[7]=f2bf(v1[3]);
      bw[ks] = o;
    }
  }

  // ---- epilogue identity: tid<512 owns (batch eb, hidden ejj) ----
  const int eb  = tid >> 4;        // 0..31 (block-local batch)
  const int ejj = tid & 15;        // 0..15 (block-local j)
  const int jg  = js * 16 + ejj;   // global j
  float bias[4] = {0.f, 0.f, 0.f, 0.f};
  if (tid < 512) {
    #pragma unroll
    for (int gi = 0; gi < 4; ++gi) bias[gi] = bx[gi * 1024 + jg] + bh[gi * 1024 + jg];
  }
  float c_reg = 0.0f, h_keep = 0.0f;

  // ---- consumer staging identity (tid >= 512): 12 units each ----
  const int k    = tid - 512;
  const int ceb  = k & 31;         // staged LDS row (batch)
  const int cjs0 = k >> 5;         // base producer slice
  const unsigned cswz = ((unsigned)(ceb & 7)) << 4;

  char* const hSB = (char*)hS;

  for (int t = 0; t < 512; ++t) {
    float4v acc[2];
    acc[0] = (float4v){0.f, 0.f, 0.f, 0.f};
    acc[1] = (float4v){0.f, 0.f, 0.f, 0.f};

    if (kq < 2) {
      // ---- P1 (x-waves): x MFMAs, no h dependency ----
      if (XBF) {
        const short* xb = xbf + ((size_t)t << 16) + kq * 512 + lh * 8;
        #pragma unroll
        for (int ks = 0; ks < 16; ++ks) {
          #pragma unroll
          for (int mt = 0; mt < 2; ++mt) {
            const int b = g * 32 + mt * 16 + l15;
            short8 a = *(const short8*)(xb + ((size_t)b << 10) + ks * 32);
            acc[mt] = __builtin_amdgcn_mfma_f32_16x16x32_bf16(a, bw[ks], acc[mt], 0, 0, 0);
          }
        }
      } else {
        const float* Ab = x + (size_t)t * 1024 + kq * 512 + lh * 8;
        #pragma unroll
        for (int ks = 0; ks < 16; ++ks) {
          #pragma unroll
          for (int mt = 0; mt < 2; ++mt) {
            const int b = g * 32 + mt * 16 + l15;
            const float* p = Ab + (size_t)b * 524288 + ks * 32;
            float4v v0 = *(const float4v*)p;
            float4v v1 = *(const float4v*)(p + 4);
            short8 a;
            a[0]=f2bf(v0[0]); a[1]=f2bf(v0[1]); a[2]=f2bf(v0[2]); a[3]=f2bf(v0[3]);
            a[4]=f2bf(v1[0]); a[5]=f2bf(v1[1]); a[6]=f2bf(v1[2]); a[7]=f2bf(v1[3]);
            acc[mt] = __builtin_amdgcn_mfma_f32_16x16x32_bf16(a, bw[ks], acc[mt], 0, 0, 0);
          }
        }
      }
      #pragma unroll
      for (int mt = 0; mt < 2; ++mt)
        #pragma unroll
        for (int r = 0; r < 4; ++r)
          red[kq][mt * 16 + lh * 4 + r][rg * 16 + l15] = acc[mt][r];
    } else {
      // ---- P1 (h-waves): pipelined tag-poll + stage (hop-collapsed) ----
      const char* rb = ring + (size_t)((g << 1) | (t & 1)) * 98304;
      const unsigned tgt = (unsigned)t;
      unsigned tg[12];
      #pragma unroll
      for (int i = 0; i < 12; ++i) {
        const char* p = rb + (size_t)(cjs0 + ((i & 3) << 4)) * 1536 + ceb * 48 + (i >> 2) * 16;
        tg[i] = __hip_atomic_load((const unsigned*)(p + 12),
                                  __ATOMIC_RELAXED, __HIP_MEMORY_SCOPE_AGENT);
      }
      for (;;) {
        unsigned miss = 0;
        #pragma unroll
        for (int i = 0; i < 12; ++i) miss |= (tg[i] < tgt) ? (1u << i) : 0u;
        if (!miss) break;
        __builtin_amdgcn_s_sleep(1);
        #pragma unroll
        for (int i = 0; i < 12; ++i) {
          if (miss & (1u << i)) {
            const char* p = rb + (size_t)(cjs0 + ((i & 3) << 4)) * 1536 + ceb * 48 + (i >> 2) * 16;
            tg[i] = __hip_atomic_load((const unsigned*)(p + 12),
                                      __ATOMIC_RELAXED, __HIP_MEMORY_SCOPE_AGENT);
          }
        }
      }
      // payload loads (pipelined) + swizzled LDS writes
      #pragma unroll
      for (int i = 0; i < 12; ++i) {
        const char* p = rb + (size_t)(cjs0 + ((i & 3) << 4)) * 1536 + ceb * 48 + (i >> 2) * 16;
        const u64 a = __hip_atomic_load((const u64*)p,
                                        __ATOMIC_RELAXED, __HIP_MEMORY_SCOPE_AGENT);
        const unsigned b = __hip_atomic_load((const unsigned*)(p + 8),
                                             __ATOMIC_RELAXED, __HIP_MEMORY_SCOPE_AGENT);
        const unsigned lb = (unsigned)ceb * 2048
                          + (unsigned)(cjs0 + ((i & 3) << 4)) * 32 + (i >> 2) * 12;
        if ((i >> 2) == 0) {
          *(u64*)(hSB + (lb ^ cswz)) = a;                       // j0..j3
          *(unsigned*)(hSB + ((lb + 8) ^ cswz)) = b;            // j4,j5
        } else if ((i >> 2) == 1) {
          *(unsigned*)(hSB + (lb ^ cswz)) = (unsigned)a;        // j6,j7 @ +12
          const u64 v = (a >> 32) | ((u64)b << 32);             // j8..j11
          *(u64*)(hSB + ((lb + 4) ^ cswz)) = v;                 // @ +16
        } else {
          *(u64*)(hSB + (lb ^ cswz)) = a;                       // j12..j15 @ +24
        }
      }
    }
    __syncthreads();   // B1: h staged (x partials already in red)

    if (kq >= 2) {
      // ---- P2 (h-waves): swizzled ds_read_b128 frags + MFMA ----
      const unsigned cb = (unsigned)((kq - 2) * 1024 + lh * 16);
      const unsigned xr = (unsigned)((l15 & 7) << 4);
      #pragma unroll
      for (int ks = 0; ks < 16; ++ks) {
        #pragma unroll
        for (int mt = 0; mt < 2; ++mt) {
          const unsigned byte = (((unsigned)(mt * 16 + l15) << 11) + cb + ks * 64) ^ xr;
          short8 a = *(const short8*)(hSB + byte);
          acc[mt] = __builtin_amdgcn_mfma_f32_16x16x32_bf16(a, bw[ks], acc[mt], 0, 0, 0);
        }
      }
      #pragma unroll
      for (int mt = 0; mt < 2; ++mt)
        #pragma unroll
        for (int r = 0; r < 4; ++r)
          red[kq][mt * 16 + lh * 4 + r][rg * 16 + l15] = acc[mt][r];
    }
    __syncthreads();   // B2: all partials in red

    if (tid < 512) {
      // ---- P3: K-reduce + gates + state + tagged-unit stores ----
      const int base = (ejj >> 2) * 16 + (ejj & 3) * 4;
      const float4v r0 = *(const float4v*)&red[0][eb][base];
      const float4v r1 = *(const float4v*)&red[1][eb][base];
      const float4v r2 = *(const float4v*)&red[2][eb][base];
      const float4v r3 = *(const float4v*)&red[3][eb][base];
      const float s0 = r0[0] + r1[0] + r2[0] + r3[0] + bias[0];
      const float s1 = r0[1] + r1[1] + r2[1] + r3[1] + bias[1];
      const float s2 = r0[2] + r1[2] + r2[2] + r3[2] + bias[2];
      const float s3 = r0[3] + r1[3] + r2[3] + r3[3] + bias[3];
      const float ig = sigm(s0);
      const float fg = sigm(s1);
      const float og = sigm(s2);
      const float gg = tanh_s(s3);
      c_reg = fg * c_reg + ig * gg;
      const float hh = og * tanh_s(c_reg);
      h_keep = hh;
      // pack 6 bf16 + tag into one 16B unit via intra-wave shfl gather
      const unsigned hv = (unsigned)(unsigned short)f2bf(hh);
      const int i3  = ejj;             // packer if < 3
      const int ebL = lane >> 4;
      const int sb  = ebL * 16 + i3 * 6;
      const unsigned v0 = (unsigned)__shfl((int)hv, sb + 0, 64);
      const unsigned v1 = (unsigned)__shfl((int)hv, sb + 1, 64);
      const unsigned v2 = (unsigned)__shfl((int)hv, sb + 2, 64);
      const unsigned v3 = (unsigned)__shfl((int)hv, sb + 3, 64);
      const unsigned v4 = (unsigned)__shfl((int)hv, sb + 4, 64);
      const unsigned v5 = (unsigned)__shfl((int)hv, sb + 5, 64);
      if (i3 < 3) {
        int4v pkt;
        pkt[0] = (int)(v0 | (v1 << 16));
        pkt[1] = (int)(v2 | (v3 << 16));
        pkt[2] = (int)(v4 | (v5 << 16));
        pkt[3] = (int)(t + 1);         // epoch tag, same 16B transaction
        char* ringN = ring + (size_t)((g << 1) | ((t + 1) & 1)) * 98304;
        char* dst = ringN + (size_t)js * 1536 + (size_t)eb * 48 + i3 * 16;
        asm volatile("global_store_dwordx4 %0, %1, off sc0 sc1"
                     :: "v"((u64)(uintptr_t)dst), "v"(pkt) : "memory");
      }
      // out store: fire-and-forget, off the cross-block chain
      out[((size_t)(g * 32 + eb) * 512 + t) * 1024 + jg] = hh;
    }
    // no B3: red/hS reuse ordered by B1/B2 + tag-wait (see header)
  }

  if (tid < 512) {
    const size_t BSH = (size_t)64 * 512 * 1024;
    out[BSH + (size_t)(g * 32 + eb) * 1024 + jg] = h_keep;
    out[BSH + 65536 + (size_t)(g * 32 + eb) * 1024 + jg] = c_reg;
  }
}

extern "C" void kernel_launch(void* const* d_in, const int* in_sizes, int n_in,
                              void* d_out, int out_size, void* d_ws, size_t ws_size,
                              hipStream_t stream) {
  (void)in_sizes; (void)n_in; (void)out_size;
  const float* x  = (const float*)d_in[0];
  const float* Wx = (const float*)d_in[1];
  const float* bx = (const float*)d_in[2];
  const float* Wh = (const float*)d_in[3];
  const float* bh = (const float*)d_in[4];
  float* out = (float*)d_out;

  char* ring  = (char*)d_ws;                                // 4 x 96 KB tagged h ring
  short* xbf  = (short*)((char*)d_ws + 393216);             // 64 MB bf16 x [t][b][d]
  const size_t need_xbf = 393216u + (size_t)64 * 512 * 1024 * 2;

  hipMemsetAsync(d_ws, 0, 393216, stream);                  // ring: h0 = 0, tags = 0

  if (ws_size >= need_xbf) {
    hipLaunchKernelGGL(xconv, dim3(16384), dim3(256), 0, stream, x, xbf);
    hipLaunchKernelGGL(lstm_persist<true>, dim3(128), dim3(1024), 0, stream,
                       x, xbf, Wx, bx, Wh, bh, out, ring);
  } else {
    hipLaunchKernelGGL(lstm_persist<false>, dim3(128), dim3(1024), 0, stream,
                       x, (const short*)d_ws, Wx, bx, Wh, bh, out, ring);
  }
}

// Round 5
// 7212.277 us; speedup vs baseline: 1.3106x; 1.3106x over previous
//
#include <hip/hip_runtime.h>

// LSTM B=64, S=512, D=H=1024 on MI355X (gfx950).
// R8: R6 skeleton + ACTIVE spinning (no s_sleep) + single-wave global poll.
// Theory: all R3-R7 variants (14-18 us/step) kept ~all waves asleep/stalled
// ~80% of wall time -> activity-driven DVFS throttles core clock ~3x; the
// ~6k-cycle/step dependency chain then takes 14 us. Keep every SIMD issuing
// (tight spins) so the governor holds frequency; consolidate L3 polling to
// one wave per block (w8), fan out via LDS flag.
// 2 recurrence groups (32 batches) x 64 j-slices = 128 blocks x 1024 thr.
// Full K=2048 weights in VGPRs (16 waves = 4 K-quarters x 4 row-groups).
// Chain per step: epi gates -> ring store -> vmcnt(0) -> LDS arrive ->
// w15 slot store -> w8 poll-hit -> LDS flag -> bulk stage -> B1 -> h MFMA.

typedef short short8 __attribute__((ext_vector_type(8)));
typedef float float4v __attribute__((ext_vector_type(4)));
typedef unsigned long long u64;

__device__ __forceinline__ short f2bf(float f) {
  union { float f; unsigned u; } v; v.f = f;
  unsigned r = (v.u + 0x7fffu + ((v.u >> 16) & 1u)) >> 16;  // RNE
  return (short)r;
}

__device__ __forceinline__ float sigm(float z) {
  float e = __expf(-fabsf(z));
  float p = 1.0f / (1.0f + e);
  return z >= 0.0f ? p : 1.0f - p;
}

__device__ __forceinline__ float tanh_s(float z) {
  float e = __expf(-2.0f * fabsf(z));
  float r = (1.0f - e) / (1.0f + e);
  return z >= 0.0f ? r : -r;
}

// one-time x fp32 [b][s][d] -> bf16 [s][b][d]
__global__ __launch_bounds__(256) void xconv(const float* __restrict__ x,
                                             short* __restrict__ xbf) {
  const int gid = blockIdx.x * 256 + threadIdx.x;
  const long i8 = (long)gid * 8;
  const int d  = (int)(i8 & 1023);
  const int bs = (int)(i8 >> 10);
  const int s  = bs & 511;
  const int b  = bs >> 9;
  const float4v* src = (const float4v*)(x + i8);
  float4v v0 = src[0], v1 = src[1];
  short8 o;
  o[0]=f2bf(v0[0]); o[1]=f2bf(v0[1]); o[2]=f2bf(v0[2]); o[3]=f2bf(v0[3]);
  o[4]=f2bf(v1[0]); o[5]=f2bf(v1[1]); o[6]=f2bf(v1[2]); o[7]=f2bf(v1[3]);
  *(short8*)(xbf + (((size_t)(s * 64 + b)) << 10) + d) = o;
}

template <bool XBF>
__global__ __launch_bounds__(1024, 4) void lstm_persist(
    const float* __restrict__ x, const short* __restrict__ xbf,
    const float* __restrict__ Wx, const float* __restrict__ bx,
    const float* __restrict__ Wh, const float* __restrict__ bh,
    float* __restrict__ out, unsigned* slots, short* hbuf)
{
  __shared__ short hS[32 * 1024];      // 64 KB staged h, XOR-swizzled rows of 2 KB
  __shared__ float red[4][32][68];     // 34.8 KB [kq][batch][n], +4 pad
  __shared__ unsigned arrive;          // epi-wave arrival counter (monotonic)
  __shared__ unsigned flag;            // release fanout (epoch)

  const int tid  = threadIdx.x;
  const int bid  = blockIdx.x;
  const int g    = bid & 1;        // batch group
  const int js   = bid >> 1;       // j-slice 0..63
  const int lane = tid & 63;
  const int w    = tid >> 6;       // wave 0..15
  const int kq   = w >> 2;         // K-quarter: 0,1 -> x, 2,3 -> h
  const int rg   = w & 3;          // row-group (16 rows each)
  const int l15  = lane & 15;
  const int lh   = lane >> 4;

  unsigned* slot_g = slots + g * 1024;            // 64 slots x 64B line each
  short* hb_g = hbuf + (size_t)g * 65536;         // 2 x 32 x 1024 bf16 ring

  // ---- static weights: 16 rows per wave, n = l15 = jj*4+gi ----
  short8 bw[16];
  {
    const int gi  = l15 & 3;
    const int jj  = l15 >> 2;
    const int row = gi * 1024 + js * 16 + rg * 4 + jj;
    const float* Wsrc = (kq < 2) ? (Wx + (size_t)row * 1024 + kq * 512)
                                 : (Wh + (size_t)row * 1024 + (kq - 2) * 512);
    #pragma unroll
    for (int ks = 0; ks < 16; ++ks) {
      const float* p = Wsrc + ks * 32 + lh * 8;
      float4v v0 = *(const float4v*)p;
      float4v v1 = *(const float4v*)(p + 4);
      short8 o;
      o[0]=f2bf(v0[0]); o[1]=f2bf(v0[1]); o[2]=f2bf(v0[2]); o[3]=f2bf(v0[3]);
      o[4]=f2bf(v1[0]); o[5]=f2bf(v1[1]); o[6]=f2bf(v1[2]); o[7]=f2bf(v1[3]);
      bw[ks] = o;
    }
  }

  // ---- epilogue identity: tid<512 owns (batch eb, hidden ejj) ----
  const int eb  = tid >> 4;        // 0..31 (block-local batch)
  const int ejj = tid & 15;        // 0..15 (block-local j)
  const int jg  = js * 16 + ejj;   // global j
  float bias[4] = {0.f, 0.f, 0.f, 0.f};
  if (tid < 512) {
    #pragma unroll
    for (int gi = 0; gi < 4; ++gi) bias[gi] = bx[gi * 1024 + jg] + bh[gi * 1024 + jg];
  }
  float c_reg = 0.0f, h_keep = 0.0f;

  if (tid == 0) {
    __hip_atomic_store(&arrive, 0u, __ATOMIC_RELAXED, __HIP_MEMORY_SCOPE_WORKGROUP);
    __hip_atomic_store(&flag,   0u, __ATOMIC_RELAXED, __HIP_MEMORY_SCOPE_WORKGROUP);
  }
  __syncthreads();

  char* const hSB = (char*)hS;

  for (int t = 0; t < 512; ++t) {
    float4v acc[2];
    acc[0] = (float4v){0.f, 0.f, 0.f, 0.f};
    acc[1] = (float4v){0.f, 0.f, 0.f, 0.f};

    if (kq < 2) {
      // ---- P1 (x-waves): x MFMAs, no h dependency ----
      if (XBF) {
        const short* xb = xbf + ((size_t)t << 16) + kq * 512 + lh * 8;
        #pragma unroll
        for (int ks = 0; ks < 16; ++ks) {
          #pragma unroll
          for (int mt = 0; mt < 2; ++mt) {
            const int b = g * 32 + mt * 16 + l15;
            short8 a = *(const short8*)(xb + ((size_t)b << 10) + ks * 32);
            acc[mt] = __builtin_amdgcn_mfma_f32_16x16x32_bf16(a, bw[ks], acc[mt], 0, 0, 0);
          }
        }
      } else {
        const float* Ab = x + (size_t)t * 1024 + kq * 512 + lh * 8;
        #pragma unroll
        for (int ks = 0; ks < 16; ++ks) {
          #pragma unroll
          for (int mt = 0; mt < 2; ++mt) {
            const int b = g * 32 + mt * 16 + l15;
            const float* p = Ab + (size_t)b * 524288 + ks * 32;
            float4v v0 = *(const float4v*)p;
            float4v v1 = *(const float4v*)(p + 4);
            short8 a;
            a[0]=f2bf(v0[0]); a[1]=f2bf(v0[1]); a[2]=f2bf(v0[2]); a[3]=f2bf(v0[3]);
            a[4]=f2bf(v1[0]); a[5]=f2bf(v1[1]); a[6]=f2bf(v1[2]); a[7]=f2bf(v1[3]);
            acc[mt] = __builtin_amdgcn_mfma_f32_16x16x32_bf16(a, bw[ks], acc[mt], 0, 0, 0);
          }
        }
      }
      #pragma unroll
      for (int mt = 0; mt < 2; ++mt)
        #pragma unroll
        for (int r = 0; r < 4; ++r)
          red[kq][mt * 16 + lh * 4 + r][rg * 16 + l15] = acc[mt][r];
    } else {
      // ---- P1 (h-waves): w8 active-polls slots; w9-15 spin LDS flag ----
      const unsigned target = (unsigned)t;
      if (w == 8) {
        const unsigned* sp = slot_g + (size_t)lane * 16;   // one slot / 64B line
        for (;;) {
          const unsigned v = __hip_atomic_load(sp, __ATOMIC_RELAXED, __HIP_MEMORY_SCOPE_AGENT);
          if (__ballot(v >= target) == ~0ull) break;       // tight, no sleep
        }
        if (lane == 0)
          __hip_atomic_store(&flag, (unsigned)(t + 1),
                             __ATOMIC_RELAXED, __HIP_MEMORY_SCOPE_WORKGROUP);
      } else {
        while (__hip_atomic_load(&flag, __ATOMIC_RELAXED, __HIP_MEMORY_SCOPE_WORKGROUP)
               < (unsigned)(t + 1)) { }                    // tight, no sleep
      }
      // bulk stage 64 KB with 512 threads: 8 pipelined 16B loads each
      __builtin_amdgcn_s_setprio(1);
      const int tau = tid - 512;
      const int row = tau >> 4;          // 0..31
      const int sec = tau & 15;          // 0..15
      const short* src = hb_g + (size_t)(t & 1) * 32768 + row * 1024 + sec * 8;
      #pragma unroll
      for (int i = 0; i < 8; ++i) {
        const u64* p = (const u64*)(src + i * 128);
        union { u64 q[2]; short8 s; } u;
        u.q[0] = __hip_atomic_load(p,     __ATOMIC_RELAXED, __HIP_MEMORY_SCOPE_AGENT);
        u.q[1] = __hip_atomic_load(p + 1, __ATOMIC_RELAXED, __HIP_MEMORY_SCOPE_AGENT);
        const unsigned byte = (((unsigned)row << 11) + sec * 16 + i * 256)
                              ^ ((unsigned)(row & 7) << 4);
        *(short8*)(hSB + byte) = u.s;
      }
      __builtin_amdgcn_s_setprio(0);
    }
    __syncthreads();   // B1: h staged (x partials already in red)

    if (kq >= 2) {
      // ---- P2 (h-waves): swizzled ds_read_b128 frags + MFMA ----
      __builtin_amdgcn_s_setprio(1);
      const unsigned cb = (unsigned)((kq - 2) * 1024 + lh * 16);
      const unsigned xr = (unsigned)((l15 & 7) << 4);
      #pragma unroll
      for (int ks = 0; ks < 16; ++ks) {
        #pragma unroll
        for (int mt = 0; mt < 2; ++mt) {
          const unsigned byte = (((unsigned)(mt * 16 + l15) << 11) + cb + ks * 64) ^ xr;
          short8 a = *(const short8*)(hSB + byte);
          acc[mt] = __builtin_amdgcn_mfma_f32_16x16x32_bf16(a, bw[ks], acc[mt], 0, 0, 0);
        }
      }
      #pragma unroll
      for (int mt = 0; mt < 2; ++mt)
        #pragma unroll
        for (int r = 0; r < 4; ++r)
          red[kq][mt * 16 + lh * 4 + r][rg * 16 + l15] = acc[mt][r];
      __builtin_amdgcn_s_setprio(0);
    }
    __syncthreads();   // B2: all partials in red

    if (tid < 512) {
      // ---- P3 (epi waves 0-7): reduce + gates + ring store + arrive ----
      const int base = (ejj >> 2) * 16 + (ejj & 3) * 4;
      const float4v r0 = *(const float4v*)&red[0][eb][base];
      const float4v r1 = *(const float4v*)&red[1][eb][base];
      const float4v r2 = *(const float4v*)&red[2][eb][base];
      const float4v r3 = *(const float4v*)&red[3][eb][base];
      const float s0 = r0[0] + r1[0] + r2[0] + r3[0] + bias[0];
      const float s1 = r0[1] + r1[1] + r2[1] + r3[1] + bias[1];
      const float s2 = r0[2] + r1[2] + r2[2] + r3[2] + bias[2];
      const float s3 = r0[3] + r1[3] + r2[3] + r3[3] + bias[3];
      const float ig = sigm(s0);
      const float fg = sigm(s1);
      const float og = sigm(s2);
      const float gg = tanh_s(s3);
      c_reg = fg * c_reg + ig * gg;
      const float hh = og * tanh_s(c_reg);
      h_keep = hh;
      // ring store (pack 2 bf16 via shfl -> one u32 sc1 store)
      unsigned hv = (unsigned)(unsigned short)f2bf(hh);
      unsigned nb = (unsigned)__shfl_xor((int)hv, 1, 64);
      if ((ejj & 1) == 0) {
        unsigned vv = hv | (nb << 16);
        unsigned* dst = (unsigned*)(hb_g + (size_t)((t + 1) & 1) * 32768 + eb * 1024 + jg);
        __hip_atomic_store(dst, vv, __ATOMIC_RELAXED, __HIP_MEMORY_SCOPE_AGENT);
      }
      // drain the ring store ONLY (B2 already drained everything else),
      // then register this wave's arrival locally (LDS, cheap).
      asm volatile("s_waitcnt vmcnt(0)" ::: "memory");
      if (lane == 0)
        __hip_atomic_fetch_add(&arrive, 1u, __ATOMIC_RELAXED, __HIP_MEMORY_SCOPE_WORKGROUP);
      // out store AFTER the arrival: fire-and-forget, drains at next B1.
      out[((size_t)(g * 32 + eb) * 512 + t) * 1024 + jg] = hh;
    } else if (w == 15) {
      // ---- block signaler: active spin on LDS counter, then slot store ----
      const unsigned tgt = 8u * (unsigned)(t + 1);
      while (__hip_atomic_load(&arrive, __ATOMIC_RELAXED, __HIP_MEMORY_SCOPE_WORKGROUP) < tgt) { }
      if (lane == 0)
        __hip_atomic_store(slot_g + (size_t)js * 16, (unsigned)(t + 1),
                           __ATOMIC_RELAXED, __HIP_MEMORY_SCOPE_AGENT);
    }
    // no B3: red/hS reuse is ordered by B1/B2 + slot/flag-wait (see header)
  }

  if (tid < 512) {
    const size_t BSH = (size_t)64 * 512 * 1024;
    out[BSH + (size_t)(g * 32 + eb) * 1024 + jg] = h_keep;
    out[BSH + 65536 + (size_t)(g * 32 + eb) * 1024 + jg] = c_reg;
  }
}

extern "C" void kernel_launch(void* const* d_in, const int* in_sizes, int n_in,
                              void* d_out, int out_size, void* d_ws, size_t ws_size,
                              hipStream_t stream) {
  (void)in_sizes; (void)n_in; (void)out_size;
  const float* x  = (const float*)d_in[0];
  const float* Wx = (const float*)d_in[1];
  const float* bx = (const float*)d_in[2];
  const float* Wh = (const float*)d_in[3];
  const float* bh = (const float*)d_in[4];
  float* out = (float*)d_out;

  unsigned* slots = (unsigned*)d_ws;                        // 8 KB: 2 x 64 slots, 64B apart
  short* hbuf     = (short*)((char*)d_ws + 8192);           // 2 groups x 2 x 64 KB h ring
  short* xbf      = (short*)((char*)d_ws + 8192 + 262144);  // 64 MB bf16 x [t][b][d]
  const size_t need_xbf = 8192u + 262144u + (size_t)64 * 512 * 1024 * 2;

  hipMemsetAsync(d_ws, 0, 8192 + 262144, stream);           // slots + h0 = 0

  if (ws_size >= need_xbf) {
    hipLaunchKernelGGL(xconv, dim3(16384), dim3(256), 0, stream, x, xbf);
    hipLaunchKernelGGL(lstm_persist<true>, dim3(128), dim3(1024), 0, stream,
                       x, xbf, Wx, bx, Wh, bh, out, slots, hbuf);
  } else {
    hipLaunchKernelGGL(lstm_persist<false>, dim3(128), dim3(1024), 0, stream,
                       x, hbuf, Wx, bx, Wh, bh, out, slots, hbuf);
  }
}